// Round 6
// baseline (387.525 us; speedup 1.0000x reference)
//
#include <hip/hip_runtime.h>
#include <hip/hip_bf16.h>
#include <stdint.h>

// ---------------------------------------------------------------------------
// MultiHeadAttention: B=2, Nq=S=2048, D=1024, H=16, dh=64, f32 in/out.
// cast->bf16, W^T transpose, QKV projection GEMM (Q pre-scaled by 1/8),
// V transpose -> [b][h][d][s], attention v3: K/V fragments loaded DIRECTLY
// from global (L1/L2-resident) in MFMA layout -- no K/V LDS, no barriers in
// the main loop. P goes through wave-private LDS with full-rank 8B swizzle.
// Softmax denom over ALL keys, strict lower-tri numerator, no renorm.
// Output projection GEMM -> f32.
// ---------------------------------------------------------------------------

typedef __bf16 bf16x8 __attribute__((ext_vector_type(8)));
typedef float f32x4 __attribute__((ext_vector_type(4)));
typedef unsigned int u32x4 __attribute__((ext_vector_type(4)));

typedef const __attribute__((address_space(1))) void* gas_t;
typedef __attribute__((address_space(3))) void* las_t;

__device__ __forceinline__ unsigned short f2bf(float f) {
    unsigned int u = __float_as_uint(f);
    return (unsigned short)((u + 0x7FFFu + ((u >> 16) & 1u)) >> 16);
}

// ---------------- cast f32 -> bf16 (queries/keys/values) -------------------
__global__ __launch_bounds__(256) void cast_qkv(
    const float* __restrict__ q, const float* __restrict__ k, const float* __restrict__ v,
    unsigned short* __restrict__ oq, unsigned short* __restrict__ ok, unsigned short* __restrict__ ov)
{
    const float* src = (blockIdx.z == 0) ? q : (blockIdx.z == 1) ? k : v;
    unsigned short* dst = (blockIdx.z == 0) ? oq : (blockIdx.z == 1) ? ok : ov;
    unsigned int i = blockIdx.x * 256u + threadIdx.x;   // float4 index
    float4 f = reinterpret_cast<const float4*>(src)[i];
    ushort4 o;
    o.x = f2bf(f.x); o.y = f2bf(f.y); o.z = f2bf(f.z); o.w = f2bf(f.w);
    reinterpret_cast<ushort4*>(dst)[i] = o;
}

// ---------------- W (1024x1024 f32) -> W^T bf16 ----------------------------
__global__ __launch_bounds__(256) void transpose_w(
    const float* __restrict__ w0, const float* __restrict__ w1,
    const float* __restrict__ w2, const float* __restrict__ w3,
    unsigned short* __restrict__ t0, unsigned short* __restrict__ t1,
    unsigned short* __restrict__ t2, unsigned short* __restrict__ t3)
{
    const float* W = (blockIdx.z == 0) ? w0 : (blockIdx.z == 1) ? w1 : (blockIdx.z == 2) ? w2 : w3;
    unsigned short* T = (blockIdx.z == 0) ? t0 : (blockIdx.z == 1) ? t1 : (blockIdx.z == 2) ? t2 : t3;
    __shared__ float s[32][33];
    const int tx = threadIdx.x, ty = threadIdx.y;   // 32 x 8
    const int x = blockIdx.x * 32 + tx;
#pragma unroll
    for (int j = 0; j < 4; ++j)
        s[ty + 8 * j][tx] = W[(size_t)(blockIdx.y * 32 + ty + 8 * j) * 1024 + x];
    __syncthreads();
    const int xo = blockIdx.y * 32 + tx;
#pragma unroll
    for (int j = 0; j < 4; ++j)
        T[(size_t)(blockIdx.x * 32 + ty + 8 * j) * 1024 + xo] = f2bf(s[tx][ty + 8 * j]);
}

// ---------------- Vp [b*2048+s][h*64+d] -> Vt [b][h][d][s] -----------------
__global__ __launch_bounds__(256) void transpose_v(
    const unsigned short* __restrict__ Vp, unsigned short* __restrict__ Vt)
{
    __shared__ unsigned short s[64][68];
    const int tid = threadIdx.x;
    const int s0 = blockIdx.x * 64, h = blockIdx.y, b = blockIdx.z;
    const size_t inbase = ((size_t)(b * 2048 + s0)) * 1024 + h * 64;
#pragma unroll
    for (int r = 0; r < 4; ++r) {
        int idx = r * 256 + tid;
        int row = idx >> 4;            // s local 0..63
        int c4 = (idx & 15) * 4;       // d local
        ushort4 v = *(const ushort4*)(Vp + inbase + (size_t)row * 1024 + c4);
        *(ushort4*)&s[row][c4] = v;
    }
    __syncthreads();
    const size_t outbase = ((size_t)((b * 16 + h) * 64)) * 2048 + s0;
#pragma unroll
    for (int r = 0; r < 4; ++r) {
        int idx = r * 256 + tid;
        int drow = idx >> 4;           // d local 0..63
        int sc = (idx & 15) * 4;       // s local
        ushort4 v;
        v.x = s[sc][drow]; v.y = s[sc + 1][drow]; v.z = s[sc + 2][drow]; v.w = s[sc + 3][drow];
        *(ushort4*)(Vt + outbase + (size_t)drow * 2048 + sc) = v;
    }
}

// ---------------- GEMM: C[M,N] = A[M,K] * Bt[N,K]^T, K=1024, bf16 ----------
// 256 threads, 2x2 waves, wave tile (BM/2)x(BN/2), BK=32, 16x16x32 MFMA.
// MODE 0: z selects (A,W,dst), bf16 row-major out; z==0 output scaled by
// 0.125 (fold 1/sqrt(dh) into Q). MODE 1: f32 out.
template <int BM, int BN, int MODE>
__global__ __launch_bounds__(256) void gemm_bt(
    const unsigned short* __restrict__ A0, const unsigned short* __restrict__ A1,
    const unsigned short* __restrict__ A2,
    const unsigned short* __restrict__ B0, const unsigned short* __restrict__ B1,
    const unsigned short* __restrict__ B2,
    unsigned short* __restrict__ C0, unsigned short* __restrict__ C1,
    unsigned short* __restrict__ C2, float* __restrict__ Cf)
{
    constexpr int K = 1024;
    constexpr int WM = BM / 2, WN = BN / 2, MI = WM / 16, NI = WN / 16;
    __shared__ __align__(16) unsigned char lds[(BM + BN) * 64];
    unsigned char* lA = lds;
    unsigned char* lB = lds + BM * 64;

    const int tid = threadIdx.x;
    const int z = blockIdx.z;
    const unsigned short* A  = (MODE == 1 || z == 0) ? A0 : (z == 1) ? A1 : A2;
    const unsigned short* Bt = (MODE == 1 || z == 0) ? B0 : (z == 1) ? B1 : B2;
    const int m0 = blockIdx.y * BM, n0 = blockIdx.x * BN;
    const int w = tid >> 6, lane = tid & 63, g = lane >> 4, l15 = lane & 15;
    const int wr = w >> 1, wc = w & 1;

    f32x4 acc[MI][NI] = {};

    for (int k0 = 0; k0 < K; k0 += 32) {
#pragma unroll
        for (int r = 0; r < (BM * 64) / 4096; ++r) {
            const int o = (r * 256 + tid) * 16;
            const unsigned char* gp = (const unsigned char*)A
                + ((size_t)(m0 + (o >> 6)) * K + k0) * 2 + (o & 63);
            __builtin_amdgcn_global_load_lds((gas_t)gp,
                (las_t)(lA + (r * 256 + (tid & ~63)) * 16), 16, 0, 0);
        }
#pragma unroll
        for (int r = 0; r < (BN * 64) / 4096; ++r) {
            const int o = (r * 256 + tid) * 16;
            const unsigned char* gp = (const unsigned char*)Bt
                + ((size_t)(n0 + (o >> 6)) * K + k0) * 2 + (o & 63);
            __builtin_amdgcn_global_load_lds((gas_t)gp,
                (las_t)(lB + (r * 256 + (tid & ~63)) * 16), 16, 0, 0);
        }
        __syncthreads();

        bf16x8 a[MI], bfr[NI];
#pragma unroll
        for (int mi = 0; mi < MI; ++mi)
            a[mi] = *(const bf16x8*)(lA + (wr * WM + mi * 16 + l15) * 64 + g * 16);
#pragma unroll
        for (int ni = 0; ni < NI; ++ni)
            bfr[ni] = *(const bf16x8*)(lB + (wc * WN + ni * 16 + l15) * 64 + g * 16);
#pragma unroll
        for (int mi = 0; mi < MI; ++mi)
#pragma unroll
            for (int ni = 0; ni < NI; ++ni)
                acc[mi][ni] = __builtin_amdgcn_mfma_f32_16x16x32_bf16(a[mi], bfr[ni], acc[mi][ni], 0, 0, 0);
        __syncthreads();
    }

    if (MODE == 1) {
#pragma unroll
        for (int mi = 0; mi < MI; ++mi)
#pragma unroll
            for (int ni = 0; ni < NI; ++ni)
#pragma unroll
                for (int i = 0; i < 4; ++i) {
                    const int row = m0 + wr * WM + mi * 16 + 4 * g + i;
                    const int col = n0 + wc * WN + ni * 16 + l15;
                    Cf[(size_t)row * 1024 + col] = acc[mi][ni][i];
                }
    } else {
        unsigned short* C = (z == 0) ? C0 : (z == 1) ? C1 : C2;
        const float qscale = (z == 0) ? 0.125f : 1.0f;   // 1/sqrt(64) into Q
#pragma unroll
        for (int mi = 0; mi < MI; ++mi)
#pragma unroll
            for (int ni = 0; ni < NI; ++ni)
#pragma unroll
                for (int i = 0; i < 4; ++i) {
                    const int row = m0 + wr * WM + mi * 16 + 4 * g + i;
                    const int col = n0 + wc * WN + ni * 16 + l15;
                    C[(size_t)row * 1024 + col] = f2bf(acc[mi][ni][i] * qscale);
                }
    }
}

// ---------------- attention v3 ---------------------------------------------
// 1024 blocks x 256 thr (4 independent waves); wave w owns q rows
// [q0+16w, q0+16w+16). K/V fragments loaded directly from global in MFMA
// layout (L1/L2-resident tiles) -- no K/V LDS, NO barriers. Swapped QK^T:
// mfma(K,Q) puts keys lane-local; P round-trips wave-private LDS with
// full-rank swizzle ^(l15<<3) (conflict-free b64 write AND read).
// Phase A/B: PV tiles (diag masked). Phase C: denominator-only tiles.
// Q pre-scaled by 1/8 in projection. Denominator reduced once at the end.
__global__ __launch_bounds__(256) void attn_kernel(
    const unsigned short* __restrict__ Qp, const unsigned short* __restrict__ Kp,
    const unsigned short* __restrict__ Vt, unsigned short* __restrict__ mrg)
{
    __shared__ __align__(16) unsigned char Ps[8192];   // [64 q][64 key] bf16, ^ (l15<<3)
    __shared__ float dden[4][16];

    const int tid = threadIdx.x;
    const int w = tid >> 6, lane = tid & 63, g = lane >> 4, l15 = lane & 15;
    const int bid = blockIdx.x;
    const int bh = (bid & 7) * 4 + ((bid >> 3) & 3);   // 4 bh per XCD
    const int qt = 31 - (bid >> 5);                    // heavy blocks first
    const int b = bh >> 4, hd = bh & 15;
    const int q0 = qt * 64;

    bf16x8 aq0, aq1;
    {
        const unsigned short* qp = Qp + ((size_t)(b * 2048 + q0 + 16 * w + l15) * 1024 + hd * 64 + g * 8);
        aq0 = *(const bf16x8*)qp;
        aq1 = *(const bf16x8*)(qp + 32);
    }

    const unsigned char* Kbase = (const unsigned char*)Kp + ((size_t)(b * 2048) * 1024 + hd * 64) * 2;
    const unsigned char* Vbase = (const unsigned char*)Vt + ((size_t)bh * 64) * 2048 * 2;

    f32x4 oacc[4] = {};
    f32x4 dsum = {0.f, 0.f, 0.f, 0.f};

    const int prow = 16 * w + l15;      // this lane's q row (block-local)
    const int pb   = prow * 128;        // Ps row base (bytes)
    const int psw  = l15 << 3;          // full-rank 8B swizzle

    // ---- phases A+B: PV tiles 0..qt (diag tile masked) ----
    for (int t = 0; t <= qt; ++t) {
        const int k0 = t * 64;
        bf16x8 kf[4][2], vf[4][2];
#pragma unroll
        for (int ni = 0; ni < 4; ++ni) {
            const unsigned char* kp = Kbase + (size_t)(k0 + ni * 16 + l15) * 2048 + g * 16;
            kf[ni][0] = *(const bf16x8*)kp;
            kf[ni][1] = *(const bf16x8*)(kp + 64);
        }
#pragma unroll
        for (int ni = 0; ni < 4; ++ni) {
            const unsigned char* vp = Vbase + (size_t)(ni * 16 + l15) * 4096 + k0 * 2 + g * 16;
            vf[ni][0] = *(const bf16x8*)vp;
            vf[ni][1] = *(const bf16x8*)(vp + 64);
        }

        f32x4 pe[4];
#pragma unroll
        for (int ni = 0; ni < 4; ++ni) {
            f32x4 s = {};
            s = __builtin_amdgcn_mfma_f32_16x16x32_bf16(kf[ni][0], aq0, s, 0, 0, 0);
            s = __builtin_amdgcn_mfma_f32_16x16x32_bf16(kf[ni][1], aq1, s, 0, 0, 0);
#pragma unroll
            for (int i = 0; i < 4; ++i) pe[ni][i] = __expf(s[i]);
            dsum += pe[ni];
        }
        if (t == qt) {                  // strict lower-triangular mask
#pragma unroll
            for (int ni = 0; ni < 4; ++ni)
#pragma unroll
                for (int i = 0; i < 4; ++i)
                    if (ni * 16 + 4 * g + i >= prow) pe[ni][i] = 0.f;
        }
        // P -> LDS (wave-private rows, conflict-free swizzle)
#pragma unroll
        for (int ni = 0; ni < 4; ++ni) {
            unsigned int lo, hi;
            asm("v_cvt_pk_bf16_f32 %0, %1, %2" : "=v"(lo) : "v"(pe[ni][0]), "v"(pe[ni][1]));
            asm("v_cvt_pk_bf16_f32 %0, %1, %2" : "=v"(hi) : "v"(pe[ni][2]), "v"(pe[ni][3]));
            uint2 pv; pv.x = lo; pv.y = hi;
            *(uint2*)(Ps + ((pb + ni * 32 + g * 8) ^ psw)) = pv;
        }
        // PV: read own P row as A-fragments, multiply direct-loaded V frags
#pragma unroll
        for (int kk = 0; kk < 2; ++kk) {
            const uint2 a0 = *(const uint2*)(Ps + ((pb + kk * 64 + g * 16) ^ psw));
            const uint2 a1 = *(const uint2*)(Ps + ((pb + kk * 64 + g * 16 + 8) ^ psw));
            u32x4 au; au.x = a0.x; au.y = a0.y; au.z = a1.x; au.w = a1.y;
            const bf16x8 pa = *(const bf16x8*)&au;
#pragma unroll
            for (int ni = 0; ni < 4; ++ni)
                oacc[ni] = __builtin_amdgcn_mfma_f32_16x16x32_bf16(pa, vf[ni][kk], oacc[ni], 0, 0, 0);
        }
    }

    // ---- phase C: denominator-only tiles qt+1..31 (no LDS, no barriers) ----
    for (int t = qt + 1; t < 32; ++t) {
        const int k0 = t * 64;
        bf16x8 kf[4][2];
#pragma unroll
        for (int ni = 0; ni < 4; ++ni) {
            const unsigned char* kp = Kbase + (size_t)(k0 + ni * 16 + l15) * 2048 + g * 16;
            kf[ni][0] = *(const bf16x8*)kp;
            kf[ni][1] = *(const bf16x8*)(kp + 64);
        }
#pragma unroll
        for (int ni = 0; ni < 4; ++ni) {
            f32x4 s = {};
            s = __builtin_amdgcn_mfma_f32_16x16x32_bf16(kf[ni][0], aq0, s, 0, 0, 0);
            s = __builtin_amdgcn_mfma_f32_16x16x32_bf16(kf[ni][1], aq1, s, 0, 0, 0);
#pragma unroll
            for (int i = 0; i < 4; ++i) dsum[i] += __expf(s[i]);
        }
    }

    // ---- final: lane-local denominator -> reduce -> realign -> write ----
    float den = dsum[0] + dsum[1] + dsum[2] + dsum[3];   // q = q0+16w+l15
    den += __shfl_xor(den, 16, 64);
    den += __shfl_xor(den, 32, 64);
    if (lane < 16) dden[w][lane] = den;          // wave-private; no barrier
    float inv[4];
#pragma unroll
    for (int i = 0; i < 4; ++i) inv[i] = 1.0f / dden[w][4 * g + i];
#pragma unroll
    for (int ni = 0; ni < 4; ++ni)
#pragma unroll
        for (int i = 0; i < 4; ++i) {
            const int row = q0 + 16 * w + 4 * g + i;
            mrg[((size_t)b * 2048 + row) * 1024 + hd * 64 + ni * 16 + l15] =
                f2bf(oacc[ni][i] * inv[i]);
        }
}

// ---------------------------------------------------------------------------
extern "C" void kernel_launch(void* const* d_in, const int* in_sizes, int n_in,
                              void* d_out, int out_size, void* d_ws, size_t ws_size,
                              hipStream_t stream)
{
    const float* q  = (const float*)d_in[0];
    const float* k  = (const float*)d_in[1];
    const float* v  = (const float*)d_in[2];
    const float* Wq = (const float*)d_in[3];
    const float* Wk = (const float*)d_in[4];
    const float* Wv = (const float*)d_in[5];
    const float* Wo = (const float*)d_in[6];
    float* out = (float*)d_out;

    unsigned short* ws = (unsigned short*)d_ws;
    const size_t TEN = (size_t)2 * 2048 * 1024;        // 4194304 elements
    unsigned short* qbf = ws;                          // later reused as Vt
    unsigned short* kbf = ws + TEN;                    // later reused as mrg
    unsigned short* vbf = ws + 2 * TEN;
    unsigned short* Wqt = ws + 3 * TEN;                // 4 x [1024][1024] W^T
    unsigned short* Wkt = Wqt + 1024 * 1024;
    unsigned short* Wvt = Wkt + 1024 * 1024;
    unsigned short* Wot = Wvt + 1024 * 1024;
    unsigned short* Qp  = ws + 4 * TEN;                // [b*2048+q][h*64+d], pre-scaled 1/8
    unsigned short* Kp  = ws + 5 * TEN;                // [b*2048+s][h*64+d]
    unsigned short* Vp  = ws + 6 * TEN;                // [b*2048+s][h*64+d]
    unsigned short* Vt  = qbf;                         // [b][h][d][s] (qbf dead)
    unsigned short* mrg = kbf;                         // (kbf dead)

    cast_qkv<<<dim3(4096, 1, 3), 256, 0, stream>>>(q, k, v, qbf, kbf, vbf);
    transpose_w<<<dim3(32, 32, 4), dim3(32, 8), 0, stream>>>(Wq, Wk, Wv, Wo, Wqt, Wkt, Wvt, Wot);
    gemm_bt<128, 128, 0><<<dim3(8, 32, 3), 256, 0, stream>>>(
        qbf, kbf, vbf, Wqt, Wkt, Wvt, Qp, Kp, Vp, nullptr);
    transpose_v<<<dim3(32, 16, 2), 256, 0, stream>>>(Vp, Vt);
    attn_kernel<<<dim3(1024, 1, 1), 256, 0, stream>>>(Qp, Kp, Vt, mrg);
    gemm_bt<64, 128, 1><<<dim3(8, 64, 1), 256, 0, stream>>>(
        mrg, nullptr, nullptr, Wot, nullptr, nullptr, nullptr, nullptr, nullptr, out);
}

// Round 8
// 228.346 us; speedup vs baseline: 1.6971x; 1.6971x over previous
//
#include <hip/hip_runtime.h>
#include <hip/hip_bf16.h>
#include <stdint.h>

// ---------------------------------------------------------------------------
// MultiHeadAttention: B=2, Nq=S=2048, D=1024, H=16, dh=64, f32 in/out.
// cast->bf16, W^T transpose, QKV projection GEMM (Q pre-scaled by
// 0.125*log2e so attention uses raw v_exp_f32 = 2^x), V transpose ->
// [b][h][d][s], attention v4: LDS-staged K/V (T14 reg prefetch), swapped
// QK^T (keys lane-local), packed cvt_pk P-writes into a full-rank-swizzled
// P buffer, lane-local denominator deferred to the end. Softmax denom over
// ALL keys, strict lower-tri numerator, no renorm. Output GEMM -> f32.
// ---------------------------------------------------------------------------

typedef __bf16 bf16x8 __attribute__((ext_vector_type(8)));
typedef float f32x4 __attribute__((ext_vector_type(4)));
typedef unsigned int u32x4 __attribute__((ext_vector_type(4)));

typedef const __attribute__((address_space(1))) void* gas_t;
typedef __attribute__((address_space(3))) void* las_t;

__device__ __forceinline__ unsigned short f2bf(float f) {
    unsigned int u = __float_as_uint(f);
    return (unsigned short)((u + 0x7FFFu + ((u >> 16) & 1u)) >> 16);
}

__device__ __forceinline__ float exp2_hw(float x) {
    float r;
    asm("v_exp_f32 %0, %1" : "=v"(r) : "v"(x));
    return r;
}

// ---------------- cast f32 -> bf16 (queries/keys/values) -------------------
__global__ __launch_bounds__(256) void cast_qkv(
    const float* __restrict__ q, const float* __restrict__ k, const float* __restrict__ v,
    unsigned short* __restrict__ oq, unsigned short* __restrict__ ok, unsigned short* __restrict__ ov)
{
    const float* src = (blockIdx.z == 0) ? q : (blockIdx.z == 1) ? k : v;
    unsigned short* dst = (blockIdx.z == 0) ? oq : (blockIdx.z == 1) ? ok : ov;
    unsigned int i = blockIdx.x * 256u + threadIdx.x;   // float4 index
    float4 f = reinterpret_cast<const float4*>(src)[i];
    ushort4 o;
    o.x = f2bf(f.x); o.y = f2bf(f.y); o.z = f2bf(f.z); o.w = f2bf(f.w);
    reinterpret_cast<ushort4*>(dst)[i] = o;
}

// ---------------- W (1024x1024 f32) -> W^T bf16 ----------------------------
__global__ __launch_bounds__(256) void transpose_w(
    const float* __restrict__ w0, const float* __restrict__ w1,
    const float* __restrict__ w2, const float* __restrict__ w3,
    unsigned short* __restrict__ t0, unsigned short* __restrict__ t1,
    unsigned short* __restrict__ t2, unsigned short* __restrict__ t3)
{
    const float* W = (blockIdx.z == 0) ? w0 : (blockIdx.z == 1) ? w1 : (blockIdx.z == 2) ? w2 : w3;
    unsigned short* T = (blockIdx.z == 0) ? t0 : (blockIdx.z == 1) ? t1 : (blockIdx.z == 2) ? t2 : t3;
    __shared__ float s[32][33];
    const int tx = threadIdx.x, ty = threadIdx.y;   // 32 x 8
    const int x = blockIdx.x * 32 + tx;
#pragma unroll
    for (int j = 0; j < 4; ++j)
        s[ty + 8 * j][tx] = W[(size_t)(blockIdx.y * 32 + ty + 8 * j) * 1024 + x];
    __syncthreads();
    const int xo = blockIdx.y * 32 + tx;
#pragma unroll
    for (int j = 0; j < 4; ++j)
        T[(size_t)(blockIdx.x * 32 + ty + 8 * j) * 1024 + xo] = f2bf(s[tx][ty + 8 * j]);
}

// ---------------- Vp [b*2048+s][h*64+d] -> Vt [b][h][d][s] -----------------
__global__ __launch_bounds__(256) void transpose_v(
    const unsigned short* __restrict__ Vp, unsigned short* __restrict__ Vt)
{
    __shared__ unsigned short s[64][68];
    const int tid = threadIdx.x;
    const int s0 = blockIdx.x * 64, h = blockIdx.y, b = blockIdx.z;
    const size_t inbase = ((size_t)(b * 2048 + s0)) * 1024 + h * 64;
#pragma unroll
    for (int r = 0; r < 4; ++r) {
        int idx = r * 256 + tid;
        int row = idx >> 4;            // s local 0..63
        int c4 = (idx & 15) * 4;       // d local
        ushort4 v = *(const ushort4*)(Vp + inbase + (size_t)row * 1024 + c4);
        *(ushort4*)&s[row][c4] = v;
    }
    __syncthreads();
    const size_t outbase = ((size_t)((b * 16 + h) * 64)) * 2048 + s0;
#pragma unroll
    for (int r = 0; r < 4; ++r) {
        int idx = r * 256 + tid;
        int drow = idx >> 4;           // d local 0..63
        int sc = (idx & 15) * 4;       // s local
        ushort4 v;
        v.x = s[sc][drow]; v.y = s[sc + 1][drow]; v.z = s[sc + 2][drow]; v.w = s[sc + 3][drow];
        *(ushort4*)(Vt + outbase + (size_t)drow * 2048 + sc) = v;
    }
}

// ---------------- GEMM: C[M,N] = A[M,K] * Bt[N,K]^T, K=1024, bf16 ----------
// 256 threads, 2x2 waves, wave tile (BM/2)x(BN/2), BK=32, 16x16x32 MFMA.
// MODE 0: z selects (A,W,dst), bf16 row-major out; z==0 output scaled by
// 0.125*log2(e) (folds 1/sqrt(dh) AND the exp->exp2 conversion into Q).
// MODE 1: f32 out.
template <int BM, int BN, int MODE>
__global__ __launch_bounds__(256) void gemm_bt(
    const unsigned short* __restrict__ A0, const unsigned short* __restrict__ A1,
    const unsigned short* __restrict__ A2,
    const unsigned short* __restrict__ B0, const unsigned short* __restrict__ B1,
    const unsigned short* __restrict__ B2,
    unsigned short* __restrict__ C0, unsigned short* __restrict__ C1,
    unsigned short* __restrict__ C2, float* __restrict__ Cf)
{
    constexpr int K = 1024;
    constexpr int WM = BM / 2, WN = BN / 2, MI = WM / 16, NI = WN / 16;
    __shared__ __align__(16) unsigned char lds[(BM + BN) * 64];
    unsigned char* lA = lds;
    unsigned char* lB = lds + BM * 64;

    const int tid = threadIdx.x;
    const int z = blockIdx.z;
    const unsigned short* A  = (MODE == 1 || z == 0) ? A0 : (z == 1) ? A1 : A2;
    const unsigned short* Bt = (MODE == 1 || z == 0) ? B0 : (z == 1) ? B1 : B2;
    const int m0 = blockIdx.y * BM, n0 = blockIdx.x * BN;
    const int w = tid >> 6, lane = tid & 63, g = lane >> 4, l15 = lane & 15;
    const int wr = w >> 1, wc = w & 1;

    f32x4 acc[MI][NI] = {};

    for (int k0 = 0; k0 < K; k0 += 32) {
#pragma unroll
        for (int r = 0; r < (BM * 64) / 4096; ++r) {
            const int o = (r * 256 + tid) * 16;
            const unsigned char* gp = (const unsigned char*)A
                + ((size_t)(m0 + (o >> 6)) * K + k0) * 2 + (o & 63);
            __builtin_amdgcn_global_load_lds((gas_t)gp,
                (las_t)(lA + (r * 256 + (tid & ~63)) * 16), 16, 0, 0);
        }
#pragma unroll
        for (int r = 0; r < (BN * 64) / 4096; ++r) {
            const int o = (r * 256 + tid) * 16;
            const unsigned char* gp = (const unsigned char*)Bt
                + ((size_t)(n0 + (o >> 6)) * K + k0) * 2 + (o & 63);
            __builtin_amdgcn_global_load_lds((gas_t)gp,
                (las_t)(lB + (r * 256 + (tid & ~63)) * 16), 16, 0, 0);
        }
        __syncthreads();

        bf16x8 a[MI], bfr[NI];
#pragma unroll
        for (int mi = 0; mi < MI; ++mi)
            a[mi] = *(const bf16x8*)(lA + (wr * WM + mi * 16 + l15) * 64 + g * 16);
#pragma unroll
        for (int ni = 0; ni < NI; ++ni)
            bfr[ni] = *(const bf16x8*)(lB + (wc * WN + ni * 16 + l15) * 64 + g * 16);
#pragma unroll
        for (int mi = 0; mi < MI; ++mi)
#pragma unroll
            for (int ni = 0; ni < NI; ++ni)
                acc[mi][ni] = __builtin_amdgcn_mfma_f32_16x16x32_bf16(a[mi], bfr[ni], acc[mi][ni], 0, 0, 0);
        __syncthreads();
    }

    if (MODE == 1) {
#pragma unroll
        for (int mi = 0; mi < MI; ++mi)
#pragma unroll
            for (int ni = 0; ni < NI; ++ni)
#pragma unroll
                for (int i = 0; i < 4; ++i) {
                    const int row = m0 + wr * WM + mi * 16 + 4 * g + i;
                    const int col = n0 + wc * WN + ni * 16 + l15;
                    Cf[(size_t)row * 1024 + col] = acc[mi][ni][i];
                }
    } else {
        unsigned short* C = (z == 0) ? C0 : (z == 1) ? C1 : C2;
        // 1/sqrt(64) * log2(e): attention uses v_exp_f32 (2^x) directly
        const float qscale = (z == 0) ? 0.18033688f : 1.0f;
#pragma unroll
        for (int mi = 0; mi < MI; ++mi)
#pragma unroll
            for (int ni = 0; ni < NI; ++ni)
#pragma unroll
                for (int i = 0; i < 4; ++i) {
                    const int row = m0 + wr * WM + mi * 16 + 4 * g + i;
                    const int col = n0 + wc * WN + ni * 16 + l15;
                    C[(size_t)row * 1024 + col] = f2bf(acc[mi][ni][i] * qscale);
                }
    }
}

// ---------------- swapped QK^T fragment + exp2 helper ----------------------
// mfma(K_frag, Q_frag): out col=q (l15), row=key (4g+i). Lane holds 4
// consecutive keys of one q. Q is pre-scaled by 0.125*log2e -> raw v_exp.
__device__ __forceinline__ f32x4 qk_exp(const unsigned char* base, int rowoff,
                                        int ni, int g, int l15,
                                        bf16x8 aq0, bf16x8 aq1)
{
    const int row = rowoff + ni * 16 + l15;
    const int sw = (row & 7) << 4;
    const bf16x8 bk0 = *(const bf16x8*)(base + ((row * 128 + g * 16) ^ sw));
    const bf16x8 bk1 = *(const bf16x8*)(base + ((row * 128 + 64 + g * 16) ^ sw));
    f32x4 t = {};
    t = __builtin_amdgcn_mfma_f32_16x16x32_bf16(bk0, aq0, t, 0, 0, 0);
    t = __builtin_amdgcn_mfma_f32_16x16x32_bf16(bk1, aq1, t, 0, 0, 0);
    f32x4 r;
#pragma unroll
    for (int i = 0; i < 4; ++i) r[i] = exp2_hw(t[i]);
    return r;
}

// ---------------- attention v4 ---------------------------------------------
// 1024 blocks x 256 thr (4 waves); wave w owns q rows [q0+16w, q0+16w+16).
// LDS-staged K/V (T14: next tile prefetched into regs during compute).
// Swapped QK^T -> keys lane-local -> packed cvt_pk P-writes into Ps with
// full-rank 8B swizzle ^((q&15)<<3) (conflict-free b64 write AND read).
// Phase A/B: PV tiles (diag masked). Phase C: denominator-only, 128-key
// groups. Denominator lane-local, reduced once at the end.
__global__ __launch_bounds__(256) void attn_kernel(
    const unsigned short* __restrict__ Qp, const unsigned short* __restrict__ Kp,
    const unsigned short* __restrict__ Vt, unsigned short* __restrict__ mrg)
{
    __shared__ __align__(16) unsigned char lds[24576];
    __shared__ float dden[4][16];
    unsigned char* Ks = lds;            // [64 s][64 d] bf16, ^((s&7)<<4)
    unsigned char* Vs = lds + 8192;     // [64 d][64 s] bf16, ^((d&7)<<4)
    unsigned char* Ps = lds + 16384;    // [64 q][64 k] bf16, ^((q&15)<<3)
    // phase C reuses lds[0..16383] as [128 s][64 d]

    const int tid = threadIdx.x;
    const int w = tid >> 6, lane = tid & 63, g = lane >> 4, l15 = lane & 15;
    const int bid = blockIdx.x;
    const int bh = (bid & 7) * 4 + ((bid >> 3) & 3);   // 4 bh per XCD
    const int qt = 31 - (bid >> 5);                    // heavy blocks first
    const int b = bh >> 4, hd = bh & 15;
    const int q0 = qt * 64;

    bf16x8 aq0, aq1;
    {
        const unsigned short* qp = Qp + ((size_t)(b * 2048 + q0 + 16 * w + l15) * 1024 + hd * 64 + g * 8);
        aq0 = *(const bf16x8*)qp;
        aq1 = *(const bf16x8*)(qp + 32);
    }

    const unsigned char* Kbase = (const unsigned char*)Kp + ((size_t)(b * 2048) * 1024 + hd * 64) * 2;
    const unsigned char* Vbase = (const unsigned char*)Vt + ((size_t)bh * 64) * 2048 * 2;

    const int o0 = tid * 16,         r0 = o0 >> 7;   // rows 0..31
    const int o1 = (256 + tid) * 16, r1 = o1 >> 7;   // rows 32..63
    const int o2 = (512 + tid) * 16, r2 = o2 >> 7;   // rows 64..95  (phase C)
    const int o3 = (768 + tid) * 16, r3 = o3 >> 7;   // rows 96..127 (phase C)

    f32x4 oacc[4] = {};
    f32x4 dsum = {0.f, 0.f, 0.f, 0.f};

    const int prow = 16 * w + l15;      // this lane's q row (block-local)
    const int pb   = prow * 128;        // Ps row base (bytes)
    const int psw  = l15 << 3;          // full-rank 8B swizzle

    uint4 kr0, kr1, vr0, vr1, cr0, cr1, cr2, cr3;
    // prologue: load K/V tile 0 into regs
    kr0 = *(const uint4*)(Kbase + (size_t)r0 * 2048 + (o0 & 127));
    kr1 = *(const uint4*)(Kbase + (size_t)r1 * 2048 + (o1 & 127));
    vr0 = *(const uint4*)(Vbase + (size_t)r0 * 4096 + (o0 & 127));
    vr1 = *(const uint4*)(Vbase + (size_t)r1 * 4096 + (o1 & 127));

    // ---- phases A+B: tiles 0..qt (PV; diag tile masked) ----
    for (int t = 0; t <= qt; ++t) {
        __syncthreads();                         // all waves done reading t-1
        *(uint4*)(Ks + (o0 ^ ((r0 & 7) << 4))) = kr0;
        *(uint4*)(Ks + (o1 ^ ((r1 & 7) << 4))) = kr1;
        *(uint4*)(Vs + (o0 ^ ((r0 & 7) << 4))) = vr0;
        *(uint4*)(Vs + (o1 ^ ((r1 & 7) << 4))) = vr1;
        if (t < qt) {                            // prefetch next PV tile
            const int k1 = (t + 1) * 64;
            kr0 = *(const uint4*)(Kbase + (size_t)(k1 + r0) * 2048 + (o0 & 127));
            kr1 = *(const uint4*)(Kbase + (size_t)(k1 + r1) * 2048 + (o1 & 127));
            vr0 = *(const uint4*)(Vbase + (size_t)r0 * 4096 + (size_t)k1 * 2 + (o0 & 127));
            vr1 = *(const uint4*)(Vbase + (size_t)r1 * 4096 + (size_t)k1 * 2 + (o1 & 127));
        } else if (qt < 31) {                    // prefetch phase-C group 0
            const int kc = (qt + 1) * 64;
            const int nk = 2048 - kc;
            cr0 = *(const uint4*)(Kbase + (size_t)(kc + r0) * 2048 + (o0 & 127));
            cr1 = *(const uint4*)(Kbase + (size_t)(kc + r1) * 2048 + (o1 & 127));
            if (nk > 64) {
                cr2 = *(const uint4*)(Kbase + (size_t)(kc + r2) * 2048 + (o2 & 127));
                cr3 = *(const uint4*)(Kbase + (size_t)(kc + r3) * 2048 + (o3 & 127));
            }
        }
        __syncthreads();                         // LDS tile t ready

        f32x4 pe[4];
#pragma unroll
        for (int ni = 0; ni < 4; ++ni) {
            pe[ni] = qk_exp(Ks, 0, ni, g, l15, aq0, aq1);
            dsum += pe[ni];                      // denominator: unmasked
        }
        if (t == qt) {                           // strict lower-triangular mask
#pragma unroll
            for (int ni = 0; ni < 4; ++ni)
#pragma unroll
                for (int i = 0; i < 4; ++i)
                    if (ni * 16 + 4 * g + i >= prow) pe[ni][i] = 0.f;
        }
        // P -> LDS (wave-private rows, conflict-free swizzle)
#pragma unroll
        for (int ni = 0; ni < 4; ++ni) {
            unsigned int lo, hi;
            asm("v_cvt_pk_bf16_f32 %0, %1, %2" : "=v"(lo) : "v"(pe[ni][0]), "v"(pe[ni][1]));
            asm("v_cvt_pk_bf16_f32 %0, %1, %2" : "=v"(hi) : "v"(pe[ni][2]), "v"(pe[ni][3]));
            uint2 pv; pv.x = lo; pv.y = hi;
            *(uint2*)(Ps + ((pb + ni * 32 + g * 8) ^ psw)) = pv;
        }
        // PV: read own P row as A-fragments, V frags from LDS
#pragma unroll
        for (int kk = 0; kk < 2; ++kk) {
            const uint2 a0 = *(const uint2*)(Ps + ((pb + kk * 64 + g * 16) ^ psw));
            const uint2 a1 = *(const uint2*)(Ps + ((pb + kk * 64 + g * 16 + 8) ^ psw));
            u32x4 au; au.x = a0.x; au.y = a0.y; au.z = a1.x; au.w = a1.y;
            const bf16x8 pa = *(const bf16x8*)&au;
#pragma unroll
            for (int ni = 0; ni < 4; ++ni) {
                const int rv = ni * 16 + l15;
                const bf16x8 bv = *(const bf16x8*)(Vs + ((rv * 128 + kk * 64 + g * 16) ^ ((rv & 7) << 4)));
                oacc[ni] = __builtin_amdgcn_mfma_f32_16x16x32_bf16(pa, bv, oacc[ni], 0, 0, 0);
            }
        }
    }

    // ---- phase C: denominator-only tail, 128-key groups, T14 staged ----
    for (int kc = (qt + 1) * 64; kc < 2048; kc += 128) {
        const int nk = min(128, 2048 - kc);
        __syncthreads();                         // readers of previous group done
        *(uint4*)(lds + (o0 ^ ((r0 & 7) << 4))) = cr0;
        *(uint4*)(lds + (o1 ^ ((r1 & 7) << 4))) = cr1;
        if (nk > 64) {
            *(uint4*)(lds + (o2 ^ ((r2 & 7) << 4))) = cr2;
            *(uint4*)(lds + (o3 ^ ((r3 & 7) << 4))) = cr3;
        }
        const int kn = kc + 128;
        if (kn < 2048) {                         // prefetch next group
            const int nk2 = 2048 - kn;
            cr0 = *(const uint4*)(Kbase + (size_t)(kn + r0) * 2048 + (o0 & 127));
            cr1 = *(const uint4*)(Kbase + (size_t)(kn + r1) * 2048 + (o1 & 127));
            if (nk2 > 64) {
                cr2 = *(const uint4*)(Kbase + (size_t)(kn + r2) * 2048 + (o2 & 127));
                cr3 = *(const uint4*)(Kbase + (size_t)(kn + r3) * 2048 + (o3 & 127));
            }
        }
        __syncthreads();
        for (int koff = 0; koff < nk; koff += 64)
#pragma unroll
            for (int ni = 0; ni < 4; ++ni)
                dsum += qk_exp(lds, koff, ni, g, l15, aq0, aq1);
    }

    // ---- final: lane-local denominator -> reduce -> realign -> write ----
    float den = dsum[0] + dsum[1] + dsum[2] + dsum[3];   // q = q0+16w+l15
    den += __shfl_xor(den, 16, 64);
    den += __shfl_xor(den, 32, 64);
    if (lane < 16) dden[w][lane] = den;          // wave-private; no barrier
    float inv[4];
#pragma unroll
    for (int i = 0; i < 4; ++i) inv[i] = 1.0f / dden[w][4 * g + i];
#pragma unroll
    for (int ni = 0; ni < 4; ++ni)
#pragma unroll
        for (int i = 0; i < 4; ++i) {
            const int row = q0 + 16 * w + 4 * g + i;
            mrg[((size_t)b * 2048 + row) * 1024 + hd * 64 + ni * 16 + l15] =
                f2bf(oacc[ni][i] * inv[i]);
        }
}

// ---------------------------------------------------------------------------
extern "C" void kernel_launch(void* const* d_in, const int* in_sizes, int n_in,
                              void* d_out, int out_size, void* d_ws, size_t ws_size,
                              hipStream_t stream)
{
    const float* q  = (const float*)d_in[0];
    const float* k  = (const float*)d_in[1];
    const float* v  = (const float*)d_in[2];
    const float* Wq = (const float*)d_in[3];
    const float* Wk = (const float*)d_in[4];
    const float* Wv = (const float*)d_in[5];
    const float* Wo = (const float*)d_in[6];
    float* out = (float*)d_out;

    unsigned short* ws = (unsigned short*)d_ws;
    const size_t TEN = (size_t)2 * 2048 * 1024;        // 4194304 elements
    unsigned short* qbf = ws;                          // later reused as Vt
    unsigned short* kbf = ws + TEN;                    // later reused as mrg
    unsigned short* vbf = ws + 2 * TEN;
    unsigned short* Wqt = ws + 3 * TEN;                // 4 x [1024][1024] W^T
    unsigned short* Wkt = Wqt + 1024 * 1024;
    unsigned short* Wvt = Wkt + 1024 * 1024;
    unsigned short* Wot = Wvt + 1024 * 1024;
    unsigned short* Qp  = ws + 4 * TEN;                // [b*2048+q][h*64+d], pre-scaled
    unsigned short* Kp  = ws + 5 * TEN;                // [b*2048+s][h*64+d]
    unsigned short* Vp  = ws + 6 * TEN;                // [b*2048+s][h*64+d]
    unsigned short* Vt  = qbf;                         // [b][h][d][s] (qbf dead)
    unsigned short* mrg = kbf;                         // (kbf dead)

    cast_qkv<<<dim3(4096, 1, 3), 256, 0, stream>>>(q, k, v, qbf, kbf, vbf);
    transpose_w<<<dim3(32, 32, 4), dim3(32, 8), 0, stream>>>(Wq, Wk, Wv, Wo, Wqt, Wkt, Wvt, Wot);
    gemm_bt<128, 128, 0><<<dim3(8, 32, 3), 256, 0, stream>>>(
        qbf, kbf, vbf, Wqt, Wkt, Wvt, Qp, Kp, Vp, nullptr);
    transpose_v<<<dim3(32, 16, 2), 256, 0, stream>>>(Vp, Vt);
    attn_kernel<<<dim3(1024, 1, 1), 256, 0, stream>>>(Qp, Kp, Vt, mrg);
    gemm_bt<64, 128, 1><<<dim3(8, 64, 1), 256, 0, stream>>>(
        mrg, nullptr, nullptr, Wot, nullptr, nullptr, nullptr, nullptr, nullptr, out);
}